// Round 1
// baseline (76.522 us; speedup 1.0000x reference)
//
#include <hip/hip_runtime.h>

// RegionCodecDict: out[b,t,idx[r][n]] = sum_m spikes[b,t,idx[r][m]] * M[r][m][n] + c[r][n]
// where M[r] = W_enc[r] @ W_dec[r]  (128x128), c[r] = b_enc[r] @ W_dec[r] + b_dec[r]
// (the reference is purely linear between the two einsums, so they collapse).
//
// ws layout (requires >= 264KB):
//   pos : int[1024]            @ 0      (inverse permutation: pos[idx_flat[q]] = q)
//   c   : float[8*128]         @ 4096
//   MT  : ushort(bf16)[8*128*128] @ 8192   MT[r][n][k] = M[r][k][n]  (B-fragment friendly)

typedef __attribute__((ext_vector_type(8))) short bf16x8;
typedef __attribute__((ext_vector_type(4))) float f32x4;
typedef __attribute__((ext_vector_type(4))) short s16x4;

#define NREG 8
#define NRD  128
#define DD   512
#define NN   1024
#define ROWS 16

static __device__ __forceinline__ unsigned short f2bf(float x) {
  union { float f; unsigned u; } v; v.f = x;
  unsigned r = v.u + 0x7fffu + ((v.u >> 16) & 1u);   // RNE
  return (unsigned short)(r >> 16);
}
static __device__ __forceinline__ float bf2f(unsigned short b) {
  union { unsigned u; float f; } v; v.u = ((unsigned)b) << 16;
  return v.f;
}

// ---------- prep: pos, c, MT (fused; blocks branch on blockIdx) ----------
__global__ __launch_bounds__(256) void prep_kernel(
    const float* __restrict__ W_enc, const float* __restrict__ b_enc,
    const float* __restrict__ W_dec, const float* __restrict__ b_dec,
    const int* __restrict__ idx, int* __restrict__ pos_ws,
    float* __restrict__ c_ws, unsigned short* __restrict__ MT_ws)
{
  __shared__ float smem[8 * DD];   // A3: 8 W_enc rows; A2: 128-float partial
  int blk = blockIdx.x, t = threadIdx.x;
  if (blk < 128) {
    // M^T[r][n][k] for k in [kt*8, kt*8+8)
    int r = blk >> 4, kt = blk & 15;
    const float* We = W_enc + (size_t)(r * NRD + kt * 8) * DD;
    for (int e = t * 4; e < 8 * DD; e += 1024)
      *(float4*)&smem[e] = *(const float4*)&We[e];
    __syncthreads();
    int n = t & 127, kg = t >> 7;
    const float* Wd = W_dec + (size_t)r * DD * NRD + n;
    const float* w0 = &smem[(kg * 4 + 0) * DD];
    const float* w1 = &smem[(kg * 4 + 1) * DD];
    const float* w2 = &smem[(kg * 4 + 2) * DD];
    const float* w3 = &smem[(kg * 4 + 3) * DD];
    float a0 = 0.f, a1 = 0.f, a2 = 0.f, a3 = 0.f;
    #pragma unroll 4
    for (int d = 0; d < DD; ++d) {
      float wd = Wd[(size_t)d * NRD];
      a0 += w0[d] * wd; a1 += w1[d] * wd; a2 += w2[d] * wd; a3 += w3[d] * wd;
    }
    int kb = kt * 8 + kg * 4;
    s16x4 o;
    o.x = (short)f2bf(a0); o.y = (short)f2bf(a1);
    o.z = (short)f2bf(a2); o.w = (short)f2bf(a3);
    *(s16x4*)(MT_ws + (size_t)(r * NRD + n) * NRD + kb) = o;
  } else if (blk < 136) {
    // c[r][n] = b_dec[r][n] + sum_d b_enc[r][d] * W_dec[r][d][n]
    int r = blk - 128;
    int n = t & 127, h = t >> 7;
    const float* Wd = W_dec + (size_t)r * DD * NRD + n;
    const float* be = b_enc + r * DD;
    float acc = 0.f;
    for (int d = h * 256; d < h * 256 + 256; ++d)
      acc += be[d] * Wd[(size_t)d * NRD];
    if (h) smem[n] = acc;
    __syncthreads();
    if (!h) c_ws[r * NRD + n] = acc + smem[n] + b_dec[r * NRD + n];
  } else if (blk == 136) {
    #pragma unroll
    for (int i = 0; i < 4; ++i) {
      int q = t * 4 + i;
      pos_ws[idx[q]] = q;   // idx is a permutation of [0,1024)
    }
  }
}

// ---------- main: stage rows (permuted, bf16, swizzled) -> per-region MFMA in place -> coalesced writeback ----------
__global__ __launch_bounds__(256) void codec_kernel(
    const float* __restrict__ spikes, const int* __restrict__ pos_ws,
    const float* __restrict__ c_ws, const unsigned short* __restrict__ MT_ws,
    float* __restrict__ out)
{
  // Xs[row][q]: bf16 at elem index row*1024 + (q ^ ((row&7)<<3))  (XOR swizzle kills
  // the 16-lane stride-2048B bank conflict on the ds_read_b128 A-fragment loads)
  __shared__ unsigned short Xs[ROWS * NN];
  int t = threadIdx.x;
  int w = t >> 6, lane = t & 63;
  size_t row0 = (size_t)blockIdx.x * ROWS;

  // ---- stage: coalesced float4 global reads, bf16 scatter into permuted LDS layout
  #pragma unroll
  for (int ch = 0; ch < 4; ++ch) {
    int j = ch * 256 + lane * 4;
    int4 p4 = *(const int4*)&pos_ws[j];
    #pragma unroll
    for (int rl = 0; rl < 4; ++rl) {
      int row = w * 4 + rl;
      float4 v = *(const float4*)&spikes[(row0 + row) * NN + j];
      int base = row * NN, sw = (row & 7) << 3;
      Xs[base + (p4.x ^ sw)] = f2bf(v.x);
      Xs[base + (p4.y ^ sw)] = f2bf(v.y);
      Xs[base + (p4.z ^ sw)] = f2bf(v.z);
      Xs[base + (p4.w ^ sw)] = f2bf(v.w);
    }
  }
  __syncthreads();

  int arow = lane & 15, ag = lane >> 4;      // A: row = lane%16, k-group = lane/16
  int asw = (arow & 7) << 3;
  for (int r = 0; r < NREG; ++r) {
    // A fragments: A[i][k] = Xp[i][r*128 + k], contiguous 8 bf16 per lane
    bf16x8 a[4];
    #pragma unroll
    for (int kt = 0; kt < 4; ++kt) {
      int q0 = r * 128 + kt * 32 + ag * 8;
      a[kt] = *(const bf16x8*)&Xs[arow * NN + (q0 ^ asw)];
    }
    // B fragments straight from L2-resident MT: B[k][j] = M[k][n] = MT[n][k]
    int n0 = w * 32 + arow;                  // wave owns cols [w*32, w*32+32)
    const bf16x8* b0 = (const bf16x8*)(MT_ws + (size_t)(r * 128 + n0) * 128 + ag * 8);
    const bf16x8* b1 = (const bf16x8*)(MT_ws + (size_t)(r * 128 + n0 + 16) * 128 + ag * 8);
    f32x4 acc0 = {0.f, 0.f, 0.f, 0.f}, acc1 = {0.f, 0.f, 0.f, 0.f};
    #pragma unroll
    for (int kt = 0; kt < 4; ++kt) {         // b0[kt*4]: kt*32 bf16 = next K-subtile row
      acc0 = __builtin_amdgcn_mfma_f32_16x16x32_bf16(a[kt], b0[kt * 4], acc0, 0, 0, 0);
      acc1 = __builtin_amdgcn_mfma_f32_16x16x32_bf16(a[kt], b1[kt * 4], acc1, 0, 0, 0);
    }
    // all waves must finish reading region r's columns before anyone overwrites them
    __syncthreads();
    float cv0 = c_ws[r * 128 + n0];
    float cv1 = c_ws[r * 128 + n0 + 16];
    #pragma unroll
    for (int v = 0; v < 4; ++v) {            // D[i][j]: i = 4*(lane/16)+v, j = lane%16
      int i = ag * 4 + v, isw = (i & 7) << 3, ib = i * NN;
      Xs[ib + ((r * 128 + n0) ^ isw)]        = f2bf(acc0[v] + cv0);
      Xs[ib + ((r * 128 + n0 + 16) ^ isw)]   = f2bf(acc1[v] + cv1);
    }
  }
  __syncthreads();

  // ---- writeback: gather from permuted LDS, coalesced float4 global stores
  #pragma unroll
  for (int ch = 0; ch < 4; ++ch) {
    int j = ch * 256 + lane * 4;
    int4 p4 = *(const int4*)&pos_ws[j];
    #pragma unroll
    for (int rl = 0; rl < 4; ++rl) {
      int row = w * 4 + rl;
      int base = row * NN, sw = (row & 7) << 3;
      float4 v;
      v.x = bf2f(Xs[base + (p4.x ^ sw)]);
      v.y = bf2f(Xs[base + (p4.y ^ sw)]);
      v.z = bf2f(Xs[base + (p4.z ^ sw)]);
      v.w = bf2f(Xs[base + (p4.w ^ sw)]);
      *(float4*)&out[(row0 + row) * NN + j] = v;
    }
  }
}

extern "C" void kernel_launch(void* const* d_in, const int* in_sizes, int n_in,
                              void* d_out, int out_size, void* d_ws, size_t ws_size,
                              hipStream_t stream) {
  const float* spikes = (const float*)d_in[0];
  const float* W_enc  = (const float*)d_in[1];
  const float* b_enc  = (const float*)d_in[2];
  const float* W_dec  = (const float*)d_in[3];
  const float* b_dec  = (const float*)d_in[4];
  const int*   idx    = (const int*)d_in[5];
  float* out = (float*)d_out;

  char* ws = (char*)d_ws;
  int*            pos_ws = (int*)ws;
  float*          c_ws   = (float*)(ws + 4096);
  unsigned short* MT_ws  = (unsigned short*)(ws + 8192);

  prep_kernel<<<137, 256, 0, stream>>>(W_enc, b_enc, W_dec, b_dec, idx,
                                       pos_ws, c_ws, MT_ws);
  codec_kernel<<<8192 / ROWS, 256, 0, stream>>>(spikes, pos_ws, c_ws, MT_ws, out);
}

// Round 2
// 59.809 us; speedup vs baseline: 1.2794x; 1.2794x over previous
//
#include <hip/hip_runtime.h>

// RegionCodecDict: out[b,t,idx[r][n]] = sum_m spikes[b,t,idx[r][m]] * M[r][m][n] + c[r][n]
// where M[r] = W_enc[r] @ W_dec[r]  (128x128), c[r] = b_enc[r] @ W_dec[r] + b_dec[r]
// (the reference is purely linear between the two einsums, so they collapse).
//
// ws layout (requires >= 264KB):
//   pos : int[1024]               @ 0     (inverse permutation: pos[idx_flat[q]] = q)
//   c   : float[8*128]            @ 4096
//   MT  : ushort(bf16)[8*128*128] @ 8192  MT[r][n][k] = M[r][k][n]  (B-fragment friendly)

typedef __attribute__((ext_vector_type(8))) short bf16x8;
typedef __attribute__((ext_vector_type(4))) float f32x4;

#define NREG 8
#define NRD  128
#define DD   512
#define NN   1024
#define ROWS 16

static __device__ __forceinline__ unsigned short f2bf(float x) {
  union { float f; unsigned u; } v; v.f = x;
  unsigned r = v.u + 0x7fffu + ((v.u >> 16) & 1u);   // RNE
  return (unsigned short)(r >> 16);
}
static __device__ __forceinline__ float bf2f(unsigned short b) {
  union { unsigned u; float f; } v; v.u = ((unsigned)b) << 16;
  return v.f;
}

// ---------- prep: MFMA-based M^T, plus c and pos ----------
// grid = 25 blocks x 256 threads:
//   blk 0..15 : GEMM  MT[r][n0..n0+64][0..128],  r = blk>>1, n0 = (blk&1)*64
//   blk 16..23: c[r][*],  r = blk-16
//   blk 24    : pos
__global__ __launch_bounds__(256) void prep_kernel(
    const float* __restrict__ W_enc, const float* __restrict__ b_enc,
    const float* __restrict__ W_dec, const float* __restrict__ b_dec,
    const int* __restrict__ idx, int* __restrict__ pos_ws,
    float* __restrict__ c_ws, unsigned short* __restrict__ MT_ws)
{
  __shared__ unsigned short lds[24576];     // As: 64x128 @0 (16KB), Bs: 128x128 @8192 (32KB)
  int blk = blockIdx.x, t = threadIdx.x;

  if (blk < 16) {
    // ---- MT[r][n][k] = sum_d Wd[d][n] * We[k][d]   via  D = A(n,d) x B(d,k)
    int r = blk >> 1, n0 = (blk & 1) * 64;
    const float* We = W_enc + (size_t)r * NRD * DD;
    const float* Wd = W_dec + (size_t)r * DD * NRD;
    unsigned short* As = lds;               // As[n][d]  (swizzled d)
    unsigned short* Bs = lds + 8192;        // Bs[k][d]  (swizzled d)
    int lane = t & 63, w = t >> 6;
    int arow = lane & 15, ag = lane >> 4;

    f32x4 acc[4][2];
    #pragma unroll
    for (int i = 0; i < 4; ++i) { acc[i][0] = (f32x4){0,0,0,0}; acc[i][1] = (f32x4){0,0,0,0}; }

    for (int dc = 0; dc < 4; ++dc) {
      int d0 = dc * 128;
      // stage As: transpose-scatter Wd[d0+dl][n0+n] -> As[n][dl ^ sw(n)]
      {
        int n = t & 63, sw = (n & 7) << 3, dl0 = t >> 6;
        #pragma unroll 8
        for (int p = 0; p < 32; ++p) {
          int dl = dl0 + p * 4;
          float v = Wd[(size_t)(d0 + dl) * NRD + n0 + n];
          As[n * 128 + (dl ^ sw)] = f2bf(v);
        }
      }
      // stage Bs: straight copy We[k][d0..d0+128] -> Bs[k][d ^ sw(k)]
      #pragma unroll
      for (int i = 0; i < 8; ++i) {
        int cid = t + i * 256;
        int k = cid >> 4, dq = (cid & 15) * 8;
        const float* src = &We[(size_t)k * DD + d0 + dq];
        float4 u = *(const float4*)src;
        float4 u2 = *(const float4*)(src + 4);
        bf16x8 pk;
        pk[0] = (short)f2bf(u.x);  pk[1] = (short)f2bf(u.y);
        pk[2] = (short)f2bf(u.z);  pk[3] = (short)f2bf(u.w);
        pk[4] = (short)f2bf(u2.x); pk[5] = (short)f2bf(u2.y);
        pk[6] = (short)f2bf(u2.z); pk[7] = (short)f2bf(u2.w);
        *(bf16x8*)&Bs[k * 128 + (dq ^ ((k & 7) << 3))] = pk;
      }
      __syncthreads();

      // MFMA: wave w owns k-cols [w*32, w*32+32)
      #pragma unroll
      for (int nt = 0; nt < 4; ++nt) {
        int nl = nt * 16 + arow, asw = (nl & 7) << 3;
        bf16x8 a[4];
        #pragma unroll
        for (int ks = 0; ks < 4; ++ks)
          a[ks] = *(const bf16x8*)&As[nl * 128 + ((ks * 32 + ag * 8) ^ asw)];
        #pragma unroll
        for (int kt = 0; kt < 2; ++kt) {
          int kk = w * 32 + kt * 16 + arow, bsw = (kk & 7) << 3;
          #pragma unroll
          for (int ks = 0; ks < 4; ++ks) {
            bf16x8 b = *(const bf16x8*)&Bs[kk * 128 + ((ks * 32 + ag * 8) ^ bsw)];
            acc[nt][kt] = __builtin_amdgcn_mfma_f32_16x16x32_bf16(a[ks], b, acc[nt][kt], 0, 0, 0);
          }
        }
      }
      __syncthreads();
    }
    // write MT: D[row=n_local][col=k]
    #pragma unroll
    for (int nt = 0; nt < 4; ++nt)
      #pragma unroll
      for (int kt = 0; kt < 2; ++kt)
        #pragma unroll
        for (int v = 0; v < 4; ++v) {
          int nl = nt * 16 + ag * 4 + v;
          int kk = w * 32 + kt * 16 + arow;
          MT_ws[(size_t)(r * NRD + n0 + nl) * NRD + kk] = f2bf(acc[nt][kt][v]);
        }
  } else if (blk < 24) {
    // ---- c[r][n] = b_dec[r][n] + sum_d b_enc[r][d] * W_dec[r][d][n]
    int r = blk - 16;
    int n = t & 127, h = t >> 7;
    const float* Wd = W_dec + (size_t)r * DD * NRD + n;
    const float* be = b_enc + (size_t)r * DD;
    float acc = 0.f;
    #pragma unroll 16
    for (int d = h * 256; d < h * 256 + 256; ++d)
      acc += be[d] * Wd[(size_t)d * NRD];
    float* sm = (float*)lds;
    if (h) sm[n] = acc;
    __syncthreads();
    if (!h) c_ws[r * NRD + n] = acc + sm[n] + b_dec[r * NRD + n];
  } else {
    #pragma unroll
    for (int i = 0; i < 4; ++i) {
      int q = t * 4 + i;
      pos_ws[idx[q]] = q;   // idx is a permutation of [0,1024)
    }
  }
}

// ---------- main: stage rows (permuted, bf16, swizzled) -> per-region MFMA in place -> coalesced writeback ----------
__global__ __launch_bounds__(256) void codec_kernel(
    const float* __restrict__ spikes, const int* __restrict__ pos_ws,
    const float* __restrict__ c_ws, const unsigned short* __restrict__ MT_ws,
    float* __restrict__ out)
{
  // Xs[row][q]: bf16 at elem index row*1024 + (q ^ ((row&7)<<3))  (XOR swizzle kills
  // the 16-lane stride-2048B bank conflict on the ds_read_b128 A-fragment loads)
  __shared__ unsigned short Xs[ROWS * NN];
  int t = threadIdx.x;
  int w = t >> 6, lane = t & 63;
  size_t row0 = (size_t)blockIdx.x * ROWS;

  // ---- stage: coalesced float4 global reads, bf16 scatter into permuted LDS layout
  #pragma unroll
  for (int ch = 0; ch < 4; ++ch) {
    int j = ch * 256 + lane * 4;
    int4 p4 = *(const int4*)&pos_ws[j];
    #pragma unroll
    for (int rl = 0; rl < 4; ++rl) {
      int row = w * 4 + rl;
      float4 v = *(const float4*)&spikes[(row0 + row) * NN + j];
      int base = row * NN, sw = (row & 7) << 3;
      Xs[base + (p4.x ^ sw)] = f2bf(v.x);
      Xs[base + (p4.y ^ sw)] = f2bf(v.y);
      Xs[base + (p4.z ^ sw)] = f2bf(v.z);
      Xs[base + (p4.w ^ sw)] = f2bf(v.w);
    }
  }
  __syncthreads();

  int arow = lane & 15, ag = lane >> 4;      // A: row = lane%16, k-group = lane/16
  int asw = (arow & 7) << 3;
  for (int r = 0; r < NREG; ++r) {
    // A fragments: A[i][k] = Xp[i][r*128 + k], contiguous 8 bf16 per lane
    bf16x8 a[4];
    #pragma unroll
    for (int kt = 0; kt < 4; ++kt) {
      int q0 = r * 128 + kt * 32 + ag * 8;
      a[kt] = *(const bf16x8*)&Xs[arow * NN + (q0 ^ asw)];
    }
    // B fragments straight from L2-resident MT: B[k][j] = M[k][n] = MT[n][k]
    int n0 = w * 32 + arow;                  // wave owns cols [w*32, w*32+32)
    const bf16x8* b0 = (const bf16x8*)(MT_ws + (size_t)(r * 128 + n0) * 128 + ag * 8);
    const bf16x8* b1 = (const bf16x8*)(MT_ws + (size_t)(r * 128 + n0 + 16) * 128 + ag * 8);
    f32x4 acc0 = {0.f, 0.f, 0.f, 0.f}, acc1 = {0.f, 0.f, 0.f, 0.f};
    #pragma unroll
    for (int kt = 0; kt < 4; ++kt) {         // b0[kt*4]: kt*32 bf16 = next K-subtile row
      acc0 = __builtin_amdgcn_mfma_f32_16x16x32_bf16(a[kt], b0[kt * 4], acc0, 0, 0, 0);
      acc1 = __builtin_amdgcn_mfma_f32_16x16x32_bf16(a[kt], b1[kt * 4], acc1, 0, 0, 0);
    }
    // all waves must finish reading region r's columns before anyone overwrites them
    __syncthreads();
    float cv0 = c_ws[r * 128 + n0];
    float cv1 = c_ws[r * 128 + n0 + 16];
    #pragma unroll
    for (int v = 0; v < 4; ++v) {            // D[i][j]: i = 4*(lane/16)+v, j = lane%16
      int i = ag * 4 + v, isw = (i & 7) << 3, ib = i * NN;
      Xs[ib + ((r * 128 + n0) ^ isw)]        = f2bf(acc0[v] + cv0);
      Xs[ib + ((r * 128 + n0 + 16) ^ isw)]   = f2bf(acc1[v] + cv1);
    }
  }
  __syncthreads();

  // ---- writeback: gather from permuted LDS, coalesced float4 global stores
  #pragma unroll
  for (int ch = 0; ch < 4; ++ch) {
    int j = ch * 256 + lane * 4;
    int4 p4 = *(const int4*)&pos_ws[j];
    #pragma unroll
    for (int rl = 0; rl < 4; ++rl) {
      int row = w * 4 + rl;
      int base = row * NN, sw = (row & 7) << 3;
      float4 v;
      v.x = bf2f(Xs[base + (p4.x ^ sw)]);
      v.y = bf2f(Xs[base + (p4.y ^ sw)]);
      v.z = bf2f(Xs[base + (p4.z ^ sw)]);
      v.w = bf2f(Xs[base + (p4.w ^ sw)]);
      *(float4*)&out[(row0 + row) * NN + j] = v;
    }
  }
}

extern "C" void kernel_launch(void* const* d_in, const int* in_sizes, int n_in,
                              void* d_out, int out_size, void* d_ws, size_t ws_size,
                              hipStream_t stream) {
  const float* spikes = (const float*)d_in[0];
  const float* W_enc  = (const float*)d_in[1];
  const float* b_enc  = (const float*)d_in[2];
  const float* W_dec  = (const float*)d_in[3];
  const float* b_dec  = (const float*)d_in[4];
  const int*   idx    = (const int*)d_in[5];
  float* out = (float*)d_out;

  char* ws = (char*)d_ws;
  int*            pos_ws = (int*)ws;
  float*          c_ws   = (float*)(ws + 4096);
  unsigned short* MT_ws  = (unsigned short*)(ws + 8192);

  prep_kernel<<<25, 256, 0, stream>>>(W_enc, b_enc, W_dec, b_dec, idx,
                                      pos_ws, c_ws, MT_ws);
  codec_kernel<<<8192 / ROWS, 256, 0, stream>>>(spikes, pos_ws, c_ws, MT_ws, out);
}

// Round 3
// 43.031 us; speedup vs baseline: 1.7783x; 1.3899x over previous
//
#include <hip/hip_runtime.h>

// RegionCodecDict: out[b,t,idx[r][n]] = sum_m spikes[b,t,idx[r][m]] * M[r][m][n] + c[r][n]
// where M[r] = W_enc[r] @ W_dec[r]  (128x128), c[r] = b_enc[r] @ W_dec[r] + b_dec[r]
// (the reference is purely linear between the two einsums, so they collapse).
//
// ws layout (~2.4 MB):
//   pos    : int[1024]               @ 0        inverse permutation
//   c      : float[8*128]            @ 4096
//   MT     : ushort(bf16)[8*128*128] @ 8192     MT[r][n][k] = M[r][k][n]
//   part   : float[32*16384]         @ 270336   per-(r,dc) 128x128 f32 GEMM partials
//   part_c : float[32*8*128]         @ 2367488  per-(r,dc,dlb) c partials

typedef __attribute__((ext_vector_type(8))) short bf16x8;
typedef __attribute__((ext_vector_type(4))) float f32x4;
typedef __attribute__((ext_vector_type(4))) short s16x4;

#define NREG 8
#define NRD  128
#define DD   512
#define NN   1024
#define ROWS 16

static __device__ __forceinline__ unsigned short f2bf(float x) {
  union { float f; unsigned u; } v; v.f = x;
  unsigned r = v.u + 0x7fffu + ((v.u >> 16) & 1u);   // RNE
  return (unsigned short)(r >> 16);
}
static __device__ __forceinline__ float bf2f(unsigned short b) {
  union { unsigned u; float f; } v; v.u = ((unsigned)b) << 16;
  return v.f;
}

// ---------- prep1: 32 GEMM-partial blocks (r x d-chunk) + 1 pos block ----------
// block (r,dc): part[(r*4+dc)][n][k] = sum_{d in chunk} Wd[d][n] * We[k][d]
// c partials accumulate on the As staging loads (f32-exact).
__global__ __launch_bounds__(256) void prep1_kernel(
    const float* __restrict__ W_enc, const float* __restrict__ b_enc,
    const float* __restrict__ W_dec, const int* __restrict__ idx,
    int* __restrict__ pos_ws, float* __restrict__ part,
    float* __restrict__ part_c)
{
  __shared__ unsigned short As[128 * 128];   // As[n][d^sw(n)]  (Wd^T slice)
  __shared__ unsigned short Bs[128 * 128];   // Bs[k][d^sw(k)]  (We slice)
  int blk = blockIdx.x, t = threadIdx.x;

  if (blk < 32) {
    int r = blk >> 2, dc = blk & 3, d0 = dc * 128;
    const float* We = W_enc + (size_t)r * NRD * DD;
    const float* Wd = W_dec + (size_t)r * DD * NRD;
    const float* be = b_enc + (size_t)r * DD;

    // stage As: transpose-scatter Wd[d0+dl][n] -> As[n][dl^sw]; fuse c partials
    int n4 = (t & 31) * 4, dlb = t >> 5;     // dlb in 0..7
    float c0 = 0.f, c1 = 0.f, c2 = 0.f, c3 = 0.f;
    #pragma unroll
    for (int p = 0; p < 16; ++p) {
      int dl = dlb + p * 8;
      float4 v = *(const float4*)&Wd[(size_t)(d0 + dl) * NRD + n4];
      float bev = be[d0 + dl];
      As[(n4 + 0) * 128 + (dl ^ (((n4 + 0) & 7) << 3))] = f2bf(v.x);
      As[(n4 + 1) * 128 + (dl ^ (((n4 + 1) & 7) << 3))] = f2bf(v.y);
      As[(n4 + 2) * 128 + (dl ^ (((n4 + 2) & 7) << 3))] = f2bf(v.z);
      As[(n4 + 3) * 128 + (dl ^ (((n4 + 3) & 7) << 3))] = f2bf(v.w);
      c0 += v.x * bev; c1 += v.y * bev; c2 += v.z * bev; c3 += v.w * bev;
    }
    {
      float4 cv; cv.x = c0; cv.y = c1; cv.z = c2; cv.w = c3;
      *(float4*)&part_c[((size_t)(r * 4 + dc) * 8 + dlb) * 128 + n4] = cv;
    }
    // stage Bs: straight copy We[k][d0..d0+128]
    #pragma unroll
    for (int i = 0; i < 8; ++i) {
      int cid = t + i * 256;
      int k = cid >> 4, dq = (cid & 15) * 8;
      const float* src = &We[(size_t)k * DD + d0 + dq];
      float4 u = *(const float4*)src;
      float4 u2 = *(const float4*)(src + 4);
      bf16x8 pk;
      pk[0] = (short)f2bf(u.x);  pk[1] = (short)f2bf(u.y);
      pk[2] = (short)f2bf(u.z);  pk[3] = (short)f2bf(u.w);
      pk[4] = (short)f2bf(u2.x); pk[5] = (short)f2bf(u2.y);
      pk[6] = (short)f2bf(u2.z); pk[7] = (short)f2bf(u2.w);
      *(bf16x8*)&Bs[k * 128 + (dq ^ ((k & 7) << 3))] = pk;
    }
    __syncthreads();

    int lane = t & 63, w = t >> 6;
    int arow = lane & 15, ag = lane >> 4;
    f32x4 acc[8][2];
    #pragma unroll
    for (int i = 0; i < 8; ++i) {
      acc[i][0] = (f32x4){0.f, 0.f, 0.f, 0.f};
      acc[i][1] = (f32x4){0.f, 0.f, 0.f, 0.f};
    }
    #pragma unroll
    for (int nt = 0; nt < 8; ++nt) {
      int nl = nt * 16 + arow, asw = (nl & 7) << 3;
      bf16x8 a[4];
      #pragma unroll
      for (int ks = 0; ks < 4; ++ks)
        a[ks] = *(const bf16x8*)&As[nl * 128 + ((ks * 32 + ag * 8) ^ asw)];
      #pragma unroll
      for (int kt = 0; kt < 2; ++kt) {
        int kk = w * 32 + kt * 16 + arow, bsw = (kk & 7) << 3;
        #pragma unroll
        for (int ks = 0; ks < 4; ++ks) {
          bf16x8 b = *(const bf16x8*)&Bs[kk * 128 + ((ks * 32 + ag * 8) ^ bsw)];
          acc[nt][kt] = __builtin_amdgcn_mfma_f32_16x16x32_bf16(a[ks], b, acc[nt][kt], 0, 0, 0);
        }
      }
    }
    float* dst = part + (size_t)(r * 4 + dc) * 16384;
    #pragma unroll
    for (int nt = 0; nt < 8; ++nt)
      #pragma unroll
      for (int kt = 0; kt < 2; ++kt)
        #pragma unroll
        for (int v = 0; v < 4; ++v)
          dst[(nt * 16 + ag * 4 + v) * 128 + (w * 32 + kt * 16 + arow)] = acc[nt][kt][v];
  } else {
    // pos block
    #pragma unroll
    for (int i = 0; i < 4; ++i) {
      int q = t * 4 + i;
      pos_ws[idx[q]] = q;
    }
  }
}

// ---------- prep2: reduce partials -> MT (bf16) and c (f32) ----------
__global__ __launch_bounds__(256) void prep2_kernel(
    const float* __restrict__ part, const float* __restrict__ part_c,
    const float* __restrict__ b_dec, unsigned short* __restrict__ MT_ws,
    float* __restrict__ c_ws)
{
  int blk = blockIdx.x, t = threadIdx.x;
  if (blk < 128) {
    int e0 = (blk * 256 + t) * 4;
    int r = e0 >> 14, off = e0 & 16383;
    const float* p = part + (size_t)r * 4 * 16384 + off;
    float4 s0 = *(const float4*)&p[0];
    float4 s1 = *(const float4*)&p[16384];
    float4 s2 = *(const float4*)&p[32768];
    float4 s3 = *(const float4*)&p[49152];
    s16x4 o;
    o.x = (short)f2bf(s0.x + s1.x + s2.x + s3.x);
    o.y = (short)f2bf(s0.y + s1.y + s2.y + s3.y);
    o.z = (short)f2bf(s0.z + s1.z + s2.z + s3.z);
    o.w = (short)f2bf(s0.w + s1.w + s2.w + s3.w);
    *(s16x4*)&MT_ws[e0] = o;
  } else if (blk < 132) {
    int e = (blk - 128) * 256 + t;
    int n = e & 127;
    int r = e >> 7;
    float s = b_dec[e];
    #pragma unroll
    for (int dc = 0; dc < 4; ++dc)
      #pragma unroll
      for (int g = 0; g < 8; ++g)
        s += part_c[((size_t)(r * 4 + dc) * 8 + g) * 128 + n];
    c_ws[e] = s;
  }
}

// ---------- main: stage rows (permuted, bf16, swizzled) -> all-region MFMA into regs -> in-place write -> coalesced writeback ----------
__global__ __launch_bounds__(256) void codec_kernel(
    const float* __restrict__ spikes, const int* __restrict__ pos_ws,
    const float* __restrict__ c_ws, const unsigned short* __restrict__ MT_ws,
    float* __restrict__ out)
{
  // Xs[row][q]: bf16 at elem index row*1024 + (q ^ ((row&7)<<3))
  __shared__ unsigned short Xs[ROWS * NN];
  int t = threadIdx.x;
  int w = t >> 6, lane = t & 63;
  int arow = lane & 15, ag = lane >> 4;
  int n0 = w * 32 + arow;                    // wave owns cols [w*32, w*32+32)
  size_t row0 = (size_t)blockIdx.x * ROWS;

  float cv0[NREG], cv1[NREG];
  #pragma unroll
  for (int r = 0; r < NREG; ++r) {
    cv0[r] = c_ws[r * 128 + n0];
    cv1[r] = c_ws[r * 128 + n0 + 16];
  }

  // ---- stage: coalesced float4 global reads, bf16 scatter into permuted LDS layout
  #pragma unroll
  for (int ch = 0; ch < 4; ++ch) {
    int j = ch * 256 + lane * 4;
    int4 p4 = *(const int4*)&pos_ws[j];
    #pragma unroll
    for (int rl = 0; rl < 4; ++rl) {
      int row = w * 4 + rl;
      float4 v = *(const float4*)&spikes[(row0 + row) * NN + j];
      int base = row * NN, sw = (row & 7) << 3;
      Xs[base + (p4.x ^ sw)] = f2bf(v.x);
      Xs[base + (p4.y ^ sw)] = f2bf(v.y);
      Xs[base + (p4.z ^ sw)] = f2bf(v.z);
      Xs[base + (p4.w ^ sw)] = f2bf(v.w);
    }
  }
  __syncthreads();

  // ---- all regions: A from LDS, B from L2-resident MT, accumulate in regs
  int asw = (arow & 7) << 3;
  f32x4 acc0[NREG], acc1[NREG];
  #pragma unroll
  for (int r = 0; r < NREG; ++r) {
    bf16x8 a[4];
    #pragma unroll
    for (int kt = 0; kt < 4; ++kt)
      a[kt] = *(const bf16x8*)&Xs[arow * NN + ((r * 128 + kt * 32 + ag * 8) ^ asw)];
    const bf16x8* b0 = (const bf16x8*)(MT_ws + (size_t)(r * 128 + n0) * 128 + ag * 8);
    const bf16x8* b1 = (const bf16x8*)(MT_ws + (size_t)(r * 128 + n0 + 16) * 128 + ag * 8);
    acc0[r] = (f32x4){0.f, 0.f, 0.f, 0.f};
    acc1[r] = (f32x4){0.f, 0.f, 0.f, 0.f};
    #pragma unroll
    for (int kt = 0; kt < 4; ++kt) {
      acc0[r] = __builtin_amdgcn_mfma_f32_16x16x32_bf16(a[kt], b0[kt * 4], acc0[r], 0, 0, 0);
      acc1[r] = __builtin_amdgcn_mfma_f32_16x16x32_bf16(a[kt], b1[kt * 4], acc1[r], 0, 0, 0);
    }
  }
  __syncthreads();   // all A-reads done before any in-place overwrite

  #pragma unroll
  for (int r = 0; r < NREG; ++r) {
    #pragma unroll
    for (int v = 0; v < 4; ++v) {            // D[i][j]: i = 4*(lane/16)+v, j = lane%16
      int i = ag * 4 + v, isw = (i & 7) << 3, ib = i * NN;
      Xs[ib + ((r * 128 + n0) ^ isw)]      = f2bf(acc0[r][v] + cv0[r]);
      Xs[ib + ((r * 128 + n0 + 16) ^ isw)] = f2bf(acc1[r][v] + cv1[r]);
    }
  }
  __syncthreads();

  // ---- writeback: gather from permuted LDS, coalesced float4 global stores
  #pragma unroll
  for (int ch = 0; ch < 4; ++ch) {
    int j = ch * 256 + lane * 4;
    int4 p4 = *(const int4*)&pos_ws[j];
    #pragma unroll
    for (int rl = 0; rl < 4; ++rl) {
      int row = w * 4 + rl;
      int base = row * NN, sw = (row & 7) << 3;
      float4 v;
      v.x = bf2f(Xs[base + (p4.x ^ sw)]);
      v.y = bf2f(Xs[base + (p4.y ^ sw)]);
      v.z = bf2f(Xs[base + (p4.z ^ sw)]);
      v.w = bf2f(Xs[base + (p4.w ^ sw)]);
      *(float4*)&out[(row0 + row) * NN + j] = v;
    }
  }
}

extern "C" void kernel_launch(void* const* d_in, const int* in_sizes, int n_in,
                              void* d_out, int out_size, void* d_ws, size_t ws_size,
                              hipStream_t stream) {
  const float* spikes = (const float*)d_in[0];
  const float* W_enc  = (const float*)d_in[1];
  const float* b_enc  = (const float*)d_in[2];
  const float* W_dec  = (const float*)d_in[3];
  const float* b_dec  = (const float*)d_in[4];
  const int*   idx    = (const int*)d_in[5];
  float* out = (float*)d_out;

  char* ws = (char*)d_ws;
  int*            pos_ws  = (int*)ws;
  float*          c_ws    = (float*)(ws + 4096);
  unsigned short* MT_ws   = (unsigned short*)(ws + 8192);
  float*          part    = (float*)(ws + 270336);
  float*          part_c  = (float*)(ws + 2367488);

  prep1_kernel<<<33, 256, 0, stream>>>(W_enc, b_enc, W_dec, idx,
                                       pos_ws, part, part_c);
  prep2_kernel<<<132, 256, 0, stream>>>(part, part_c, b_dec, MT_ws, c_ws);
  codec_kernel<<<8192 / ROWS, 256, 0, stream>>>(spikes, pos_ws, c_ws, MT_ws, out);
}

// Round 4
// 39.646 us; speedup vs baseline: 1.9301x; 1.0854x over previous
//
#include <hip/hip_runtime.h>

// RegionCodecDict: out[b,t,idx[r][n]] = sum_m spikes[b,t,idx[r][m]] * M[r][m][n] + c[r][n]
// where M[r] = W_enc[r] @ W_dec[r]  (128x128), c[r] = b_enc[r] @ W_dec[r] + b_dec[r]
// (the reference is purely linear between the two einsums, so they collapse).
//
// ws layout (~2.4 MB):
//   pos    : int[1024]               @ 0        inverse permutation
//   c      : float[8*128]            @ 4096
//   MT     : ushort(bf16)[8*128*128] @ 8192     MT[r][n][k] = M[r][k][n]
//   part   : float[32*16384]         @ 270336   per-(r,dc) 128x128 f32 GEMM partials
//   part_c : float[32*8*128]         @ 2367488  per-(r,dc,dlb) c partials

typedef __attribute__((ext_vector_type(8))) short bf16x8;
typedef __attribute__((ext_vector_type(4))) float f32x4;
typedef __attribute__((ext_vector_type(4))) short s16x4;

#define NREG 8
#define NRD  128
#define DD   512
#define NN   1024
#define ROWS 16

static __device__ __forceinline__ unsigned short f2bf(float x) {
  union { float f; unsigned u; } v; v.f = x;
  unsigned r = v.u + 0x7fffu + ((v.u >> 16) & 1u);   // RNE
  return (unsigned short)(r >> 16);
}
static __device__ __forceinline__ float bf2f(unsigned short b) {
  union { unsigned u; float f; } v; v.u = ((unsigned)b) << 16;
  return v.f;
}

// ---------- prep1: 32 GEMM-partial blocks (r x d-chunk) + 1 pos block ----------
__global__ __launch_bounds__(256) void prep1_kernel(
    const float* __restrict__ W_enc, const float* __restrict__ b_enc,
    const float* __restrict__ W_dec, const int* __restrict__ idx,
    int* __restrict__ pos_ws, float* __restrict__ part,
    float* __restrict__ part_c)
{
  __shared__ unsigned short As[128 * 128];   // As[n][d^sw(n)]  (Wd^T slice)
  __shared__ unsigned short Bs[128 * 128];   // Bs[k][d^sw(k)]  (We slice)
  int blk = blockIdx.x, t = threadIdx.x;

  if (blk < 32) {
    int r = blk >> 2, dc = blk & 3, d0 = dc * 128;
    const float* We = W_enc + (size_t)r * NRD * DD;
    const float* Wd = W_dec + (size_t)r * DD * NRD;
    const float* be = b_enc + (size_t)r * DD;

    // stage As: transpose-scatter Wd[d0+dl][n] -> As[n][dl^sw]; fuse c partials
    int n4 = (t & 31) * 4, dlb = t >> 5;     // dlb in 0..7
    float c0 = 0.f, c1 = 0.f, c2 = 0.f, c3 = 0.f;
    #pragma unroll
    for (int p = 0; p < 16; ++p) {
      int dl = dlb + p * 8;
      float4 v = *(const float4*)&Wd[(size_t)(d0 + dl) * NRD + n4];
      float bev = be[d0 + dl];
      As[(n4 + 0) * 128 + (dl ^ (((n4 + 0) & 7) << 3))] = f2bf(v.x);
      As[(n4 + 1) * 128 + (dl ^ (((n4 + 1) & 7) << 3))] = f2bf(v.y);
      As[(n4 + 2) * 128 + (dl ^ (((n4 + 2) & 7) << 3))] = f2bf(v.z);
      As[(n4 + 3) * 128 + (dl ^ (((n4 + 3) & 7) << 3))] = f2bf(v.w);
      c0 += v.x * bev; c1 += v.y * bev; c2 += v.z * bev; c3 += v.w * bev;
    }
    {
      float4 cv; cv.x = c0; cv.y = c1; cv.z = c2; cv.w = c3;
      *(float4*)&part_c[((size_t)(r * 4 + dc) * 8 + dlb) * 128 + n4] = cv;
    }
    // stage Bs: straight copy We[k][d0..d0+128]
    #pragma unroll
    for (int i = 0; i < 8; ++i) {
      int cid = t + i * 256;
      int k = cid >> 4, dq = (cid & 15) * 8;
      const float* src = &We[(size_t)k * DD + d0 + dq];
      float4 u = *(const float4*)src;
      float4 u2 = *(const float4*)(src + 4);
      bf16x8 pk;
      pk[0] = (short)f2bf(u.x);  pk[1] = (short)f2bf(u.y);
      pk[2] = (short)f2bf(u.z);  pk[3] = (short)f2bf(u.w);
      pk[4] = (short)f2bf(u2.x); pk[5] = (short)f2bf(u2.y);
      pk[6] = (short)f2bf(u2.z); pk[7] = (short)f2bf(u2.w);
      *(bf16x8*)&Bs[k * 128 + (dq ^ ((k & 7) << 3))] = pk;
    }
    __syncthreads();

    int lane = t & 63, w = t >> 6;
    int arow = lane & 15, ag = lane >> 4;
    f32x4 acc[8][2];
    #pragma unroll
    for (int i = 0; i < 8; ++i) {
      acc[i][0] = (f32x4){0.f, 0.f, 0.f, 0.f};
      acc[i][1] = (f32x4){0.f, 0.f, 0.f, 0.f};
    }
    #pragma unroll
    for (int nt = 0; nt < 8; ++nt) {
      int nl = nt * 16 + arow, asw = (nl & 7) << 3;
      bf16x8 a[4];
      #pragma unroll
      for (int ks = 0; ks < 4; ++ks)
        a[ks] = *(const bf16x8*)&As[nl * 128 + ((ks * 32 + ag * 8) ^ asw)];
      #pragma unroll
      for (int kt = 0; kt < 2; ++kt) {
        int kk = w * 32 + kt * 16 + arow, bsw = (kk & 7) << 3;
        #pragma unroll
        for (int ks = 0; ks < 4; ++ks) {
          bf16x8 b = *(const bf16x8*)&Bs[kk * 128 + ((ks * 32 + ag * 8) ^ bsw)];
          acc[nt][kt] = __builtin_amdgcn_mfma_f32_16x16x32_bf16(a[ks], b, acc[nt][kt], 0, 0, 0);
        }
      }
    }
    float* dst = part + (size_t)(r * 4 + dc) * 16384;
    #pragma unroll
    for (int nt = 0; nt < 8; ++nt)
      #pragma unroll
      for (int kt = 0; kt < 2; ++kt)
        #pragma unroll
        for (int v = 0; v < 4; ++v)
          dst[(nt * 16 + ag * 4 + v) * 128 + (w * 32 + kt * 16 + arow)] = acc[nt][kt][v];
  } else {
    // pos block
    #pragma unroll
    for (int i = 0; i < 4; ++i) {
      int q = t * 4 + i;
      pos_ws[idx[q]] = q;
    }
  }
}

// ---------- prep2: reduce partials -> MT (bf16) and c (f32) ----------
__global__ __launch_bounds__(256) void prep2_kernel(
    const float* __restrict__ part, const float* __restrict__ part_c,
    const float* __restrict__ b_dec, unsigned short* __restrict__ MT_ws,
    float* __restrict__ c_ws)
{
  int blk = blockIdx.x, t = threadIdx.x;
  if (blk < 128) {
    int e0 = (blk * 256 + t) * 4;
    int r = e0 >> 14, off = e0 & 16383;
    const float* p = part + (size_t)r * 4 * 16384 + off;
    float4 s0 = *(const float4*)&p[0];
    float4 s1 = *(const float4*)&p[16384];
    float4 s2 = *(const float4*)&p[32768];
    float4 s3 = *(const float4*)&p[49152];
    s16x4 o;
    o.x = (short)f2bf(s0.x + s1.x + s2.x + s3.x);
    o.y = (short)f2bf(s0.y + s1.y + s2.y + s3.y);
    o.z = (short)f2bf(s0.z + s1.z + s2.z + s3.z);
    o.w = (short)f2bf(s0.w + s1.w + s2.w + s3.w);
    *(s16x4*)&MT_ws[e0] = o;
  } else if (blk < 132) {
    int e = (blk - 128) * 256 + t;
    int n = e & 127;
    int r = e >> 7;
    float s = b_dec[e];
    #pragma unroll
    for (int dc = 0; dc < 4; ++dc)
      #pragma unroll
      for (int g = 0; g < 8; ++g)
        s += part_c[((size_t)(r * 4 + dc) * 8 + g) * 128 + n];
    c_ws[e] = s;
  }
}

// ---------- main codec: 512 threads, 8 waves x 16 cols, separate Ys buffer ----------
// phases: stage(permuted bf16 scatter) -> B -> per-region MFMA -> Ys -> B -> gather
__global__ __launch_bounds__(512) void codec_kernel(
    const float* __restrict__ spikes, const int* __restrict__ pos_ws,
    const float* __restrict__ c_ws, const unsigned short* __restrict__ MT_ws,
    float* __restrict__ out)
{
  // Xs/Ys[row][q]: bf16 at elem index row*1024 + (q ^ ((row&7)<<3))
  __shared__ unsigned short Xs[ROWS * NN];   // 32KB input (region-permuted)
  __shared__ unsigned short Ys[ROWS * NN];   // 32KB output (region-permuted)
  int t = threadIdx.x;
  int w = t >> 6, lane = t & 63;             // 8 waves
  int arow = lane & 15, ag = lane >> 4;
  int n0 = w * 16 + arow;                    // wave w owns cols [16w, 16w+16)
  size_t row0 = (size_t)blockIdx.x * ROWS;

  // register-cached permutation (used in stage AND gather) and bias
  int4 p4c[4];
  #pragma unroll
  for (int ch = 0; ch < 4; ++ch)
    p4c[ch] = *(const int4*)&pos_ws[ch * 256 + lane * 4];
  float cv[NREG];
  #pragma unroll
  for (int r = 0; r < NREG; ++r)
    cv[r] = c_ws[r * 128 + n0];

  // ---- stage: coalesced float4 reads (2 rows per wave), bf16 scatter into permuted LDS
  #pragma unroll
  for (int ch = 0; ch < 4; ++ch) {
    int j = ch * 256 + lane * 4;
    int4 p4 = p4c[ch];
    #pragma unroll
    for (int rl = 0; rl < 2; ++rl) {
      int row = w * 2 + rl;
      float4 v = *(const float4*)&spikes[(row0 + row) * NN + j];
      int base = row * NN, sw = (row & 7) << 3;
      Xs[base + (p4.x ^ sw)] = f2bf(v.x);
      Xs[base + (p4.y ^ sw)] = f2bf(v.y);
      Xs[base + (p4.z ^ sw)] = f2bf(v.z);
      Xs[base + (p4.w ^ sw)] = f2bf(v.w);
    }
  }
  __syncthreads();

  // ---- per region: A from LDS (swizzled), B from L2-resident MT, write Ys
  int asw = (arow & 7) << 3;
  #pragma unroll
  for (int r = 0; r < NREG; ++r) {
    bf16x8 a[4];
    #pragma unroll
    for (int kt = 0; kt < 4; ++kt)
      a[kt] = *(const bf16x8*)&Xs[arow * NN + ((r * 128 + kt * 32 + ag * 8) ^ asw)];
    const bf16x8* b = (const bf16x8*)(MT_ws + (size_t)(r * 128 + n0) * 128 + ag * 8);
    f32x4 acc = {0.f, 0.f, 0.f, 0.f};
    #pragma unroll
    for (int kt = 0; kt < 4; ++kt)          // b[kt*4]: +32 bf16 = next K-subtile
      acc = __builtin_amdgcn_mfma_f32_16x16x32_bf16(a[kt], b[kt * 4], acc, 0, 0, 0);
    #pragma unroll
    for (int v = 0; v < 4; ++v) {           // D[i][j]: i = 4*(lane/16)+v, j = lane%16
      int i = ag * 4 + v, isw = (i & 7) << 3;
      Ys[i * NN + ((r * 128 + n0) ^ isw)] = f2bf(acc[v] + cv[r]);
    }
  }
  __syncthreads();

  // ---- writeback: gather from permuted Ys, coalesced float4 stores
  #pragma unroll
  for (int ch = 0; ch < 4; ++ch) {
    int j = ch * 256 + lane * 4;
    int4 p4 = p4c[ch];
    #pragma unroll
    for (int rl = 0; rl < 2; ++rl) {
      int row = w * 2 + rl;
      int base = row * NN, sw = (row & 7) << 3;
      float4 v;
      v.x = bf2f(Ys[base + (p4.x ^ sw)]);
      v.y = bf2f(Ys[base + (p4.y ^ sw)]);
      v.z = bf2f(Ys[base + (p4.z ^ sw)]);
      v.w = bf2f(Ys[base + (p4.w ^ sw)]);
      *(float4*)&out[(row0 + row) * NN + j] = v;
    }
  }
}

extern "C" void kernel_launch(void* const* d_in, const int* in_sizes, int n_in,
                              void* d_out, int out_size, void* d_ws, size_t ws_size,
                              hipStream_t stream) {
  const float* spikes = (const float*)d_in[0];
  const float* W_enc  = (const float*)d_in[1];
  const float* b_enc  = (const float*)d_in[2];
  const float* W_dec  = (const float*)d_in[3];
  const float* b_dec  = (const float*)d_in[4];
  const int*   idx    = (const int*)d_in[5];
  float* out = (float*)d_out;

  char* ws = (char*)d_ws;
  int*            pos_ws  = (int*)ws;
  float*          c_ws    = (float*)(ws + 4096);
  unsigned short* MT_ws   = (unsigned short*)(ws + 8192);
  float*          part    = (float*)(ws + 270336);
  float*          part_c  = (float*)(ws + 2367488);

  prep1_kernel<<<33, 256, 0, stream>>>(W_enc, b_enc, W_dec, idx,
                                       pos_ws, part, part_c);
  prep2_kernel<<<132, 256, 0, stream>>>(part, part_c, b_dec, MT_ws, c_ws);
  codec_kernel<<<8192 / ROWS, 512, 0, stream>>>(spikes, pos_ws, c_ws, MT_ws, out);
}